// Round 4
// baseline (2115.443 us; speedup 1.0000x reference)
//
#include <hip/hip_runtime.h>

#define DIM 128
#define BN_EPS 1e-5f
typedef unsigned int u32;

__device__ __forceinline__ u32 bf16rne(float x) {
  u32 u = __float_as_uint(x);
  return (u + 0x7FFFu + ((u >> 16) & 1u)) >> 16;
}
__device__ __forceinline__ float bflo(u32 u) { return __uint_as_float(u << 16); }
__device__ __forceinline__ float bfhi(u32 u) { return __uint_as_float(u & 0xFFFF0000u); }

// ---------------- CSR build ----------------

__global__ __launch_bounds__(256) void k_count(const int* __restrict__ dst,
                                               int* __restrict__ ideg, int ne) {
  int stride = gridDim.x * blockDim.x;
  for (int e = blockIdx.x * blockDim.x + threadIdx.x; e < ne; e += stride)
    atomicAdd(&ideg[dst[e]], 1);
}

__global__ __launch_bounds__(1024) void k_scan(const int* __restrict__ ideg,
                                               int* __restrict__ off,
                                               int* __restrict__ cur, int n) {
  __shared__ int sums[1024];
  int t = threadIdx.x;
  int chunk = (n + 1023) >> 10;
  int s0 = t * chunk;
  int s1 = s0 + chunk;
  if (s0 > n) s0 = n;
  if (s1 > n) s1 = n;
  int tot = 0;
  for (int i = s0; i < s1; ++i) tot += ideg[i];
  sums[t] = tot;
  __syncthreads();
  for (int d = 1; d < 1024; d <<= 1) {
    int v = (t >= d) ? sums[t - d] : 0;
    __syncthreads();
    sums[t] += v;
    __syncthreads();
  }
  int run = (t == 0) ? 0 : sums[t - 1];
  for (int i = s0; i < s1; ++i) {
    off[i] = run;
    cur[i] = run;
    run += ideg[i];
  }
  if (t == 1023) off[n] = run;
}

__global__ __launch_bounds__(256) void k_dinv(const int* __restrict__ ideg,
                                              float* __restrict__ dinv, int n) {
  int i = blockIdx.x * blockDim.x + threadIdx.x;
  if (i < n) dinv[i] = rsqrtf((float)ideg[i] + 1.0f);  // +1 = self loop
}

__global__ __launch_bounds__(256) void k_fill(const int* __restrict__ src,
                                              const int* __restrict__ dst,
                                              int* __restrict__ cur,
                                              int* __restrict__ csr_src, int ne) {
  int stride = gridDim.x * blockDim.x;
  for (int e = blockIdx.x * blockDim.x + threadIdx.x; e < ne; e += stride) {
    int d = dst[e];
    int s = src[e];
    int p = atomicAdd(&cur[d], 1);
    csr_src[p] = s;
  }
}

// ---------------- GEMM: C_bf16[n,128] = dinv[row] * (f(A)[n,128] @ W[128,128]) ----
// f(A) = relu(A*sc+sh) when sc != null (fused BN of previous layer), else A.

__global__ __launch_bounds__(256) void k_gemm(const float* __restrict__ A,
                                              const float* __restrict__ W,
                                              const float* __restrict__ dinv,
                                              const float* __restrict__ sc,
                                              const float* __restrict__ sh,
                                              u32* __restrict__ C, int n) {
  __shared__ float sW[DIM][DIM];
  __shared__ float sH[DIM][DIM];
  int tid = threadIdx.x;
  int row0 = blockIdx.x * DIM;

  {
    const float4* Wv = (const float4*)W;
    float4* sWv = (float4*)&sW[0][0];
    for (int i = tid; i < DIM * DIM / 4; i += 256) sWv[i] = Wv[i];
  }
  {
    float4* sHv = (float4*)&sH[0][0];
    for (int i = tid; i < DIM * DIM / 4; i += 256) {
      int r = i >> 5;
      int cg = i & 31;
      int gr = row0 + r;
      float4 v = make_float4(0.f, 0.f, 0.f, 0.f);
      if (gr < n) {
        v = ((const float4*)A)[(size_t)gr * (DIM / 4) + cg];
        if (sc) {
          float4 s4 = ((const float4*)sc)[cg];
          float4 h4 = ((const float4*)sh)[cg];
          v.x = fmaxf(fmaf(v.x, s4.x, h4.x), 0.f);
          v.y = fmaxf(fmaf(v.y, s4.y, h4.y), 0.f);
          v.z = fmaxf(fmaf(v.z, s4.z, h4.z), 0.f);
          v.w = fmaxf(fmaf(v.w, s4.w, h4.w), 0.f);
        }
      }
      sHv[i] = v;
    }
  }
  __syncthreads();

  int tx = tid & 15;
  int ty = tid >> 4;
  int c0 = tx * 8;
  int r0 = ty * 8;
  float acc[8][8];
#pragma unroll
  for (int i = 0; i < 8; ++i)
#pragma unroll
    for (int j = 0; j < 8; ++j) acc[i][j] = 0.f;

  for (int k = 0; k < DIM; ++k) {
    float4 b0 = *(const float4*)&sW[k][c0];
    float4 b1 = *(const float4*)&sW[k][c0 + 4];
    float b[8] = {b0.x, b0.y, b0.z, b0.w, b1.x, b1.y, b1.z, b1.w};
    float a[8];
#pragma unroll
    for (int i = 0; i < 8; ++i) a[i] = sH[r0 + i][k];
#pragma unroll
    for (int i = 0; i < 8; ++i)
#pragma unroll
      for (int j = 0; j < 8; ++j) acc[i][j] = fmaf(a[i], b[j], acc[i][j]);
  }

#pragma unroll
  for (int i = 0; i < 8; ++i) {
    int gr = row0 + r0 + i;
    if (gr < n) {
      float di = dinv[gr];
      uint4 p;
      p.x = bf16rne(di * acc[i][0]) | (bf16rne(di * acc[i][1]) << 16);
      p.y = bf16rne(di * acc[i][2]) | (bf16rne(di * acc[i][3]) << 16);
      p.z = bf16rne(di * acc[i][4]) | (bf16rne(di * acc[i][5]) << 16);
      p.w = bf16rne(di * acc[i][6]) | (bf16rne(di * acc[i][7]) << 16);
      ((uint4*)C)[(size_t)gr * 16 + tx] = p;
    }
  }
}

// ---------------- Aggregation + bias + residual + BN partial stats ----------------
// xw rows are bf16, pre-scaled by dinv[row]. 16 threads per node, uint4 (8 bf16) per lane.
// prev is raw pre-BN f32; if psc given, residual = relu(prev*psc+psh).

__global__ __launch_bounds__(256) void k_agg(const u32* __restrict__ xw,
                                             const int* __restrict__ off,
                                             const int* __restrict__ csr_src,
                                             const float* __restrict__ dinv,
                                             const float* __restrict__ bias,
                                             const float* __restrict__ prev,
                                             const float* __restrict__ psc,
                                             const float* __restrict__ psh,
                                             float* __restrict__ out,
                                             float* __restrict__ ssum,
                                             float* __restrict__ ssq, int n) {
  int tid = threadIdx.x;
  int lane = tid & 15;  // cols [lane*8, lane*8+8)
  int grp = tid >> 4;   // 16 node slots per block
  const uint4* xw4 = (const uint4*)xw;
  float4 bc0 = ((const float4*)bias)[lane * 2];
  float4 bc1 = ((const float4*)bias)[lane * 2 + 1];
  float4 ps0, ps1, ph0, ph1;
  if (psc) {
    ps0 = ((const float4*)psc)[lane * 2];
    ps1 = ((const float4*)psc)[lane * 2 + 1];
    ph0 = ((const float4*)psh)[lane * 2];
    ph1 = ((const float4*)psh)[lane * 2 + 1];
  }
  float lsum[8], lsq[8];
#pragma unroll
  for (int j = 0; j < 8; ++j) lsum[j] = lsq[j] = 0.f;

  for (int node = blockIdx.x * 16 + grp; node < n; node += gridDim.x * 16) {
    int e0 = off[node];
    int e1 = off[node + 1];
    float acc[8];
    {
      uint4 s = xw4[(size_t)node * 16 + lane];  // self loop
      acc[0] = bflo(s.x); acc[1] = bfhi(s.x);
      acc[2] = bflo(s.y); acc[3] = bfhi(s.y);
      acc[4] = bflo(s.z); acc[5] = bfhi(s.z);
      acc[6] = bflo(s.w); acc[7] = bfhi(s.w);
    }
    int e = e0;
    for (; e + 4 <= e1; e += 4) {
      int i0 = csr_src[e];
      int i1 = csr_src[e + 1];
      int i2 = csr_src[e + 2];
      int i3 = csr_src[e + 3];
      uint4 a = xw4[(size_t)i0 * 16 + lane];
      uint4 b = xw4[(size_t)i1 * 16 + lane];
      uint4 c = xw4[(size_t)i2 * 16 + lane];
      uint4 d = xw4[(size_t)i3 * 16 + lane];
      acc[0] += (bflo(a.x) + bflo(b.x)) + (bflo(c.x) + bflo(d.x));
      acc[1] += (bfhi(a.x) + bfhi(b.x)) + (bfhi(c.x) + bfhi(d.x));
      acc[2] += (bflo(a.y) + bflo(b.y)) + (bflo(c.y) + bflo(d.y));
      acc[3] += (bfhi(a.y) + bfhi(b.y)) + (bfhi(c.y) + bfhi(d.y));
      acc[4] += (bflo(a.z) + bflo(b.z)) + (bflo(c.z) + bflo(d.z));
      acc[5] += (bfhi(a.z) + bfhi(b.z)) + (bfhi(c.z) + bfhi(d.z));
      acc[6] += (bflo(a.w) + bflo(b.w)) + (bflo(c.w) + bflo(d.w));
      acc[7] += (bfhi(a.w) + bfhi(b.w)) + (bfhi(c.w) + bfhi(d.w));
    }
    for (; e < e1; ++e) {
      uint4 a = xw4[(size_t)csr_src[e] * 16 + lane];
      acc[0] += bflo(a.x); acc[1] += bfhi(a.x);
      acc[2] += bflo(a.y); acc[3] += bfhi(a.y);
      acc[4] += bflo(a.z); acc[5] += bfhi(a.z);
      acc[6] += bflo(a.w); acc[7] += bfhi(a.w);
    }
    float di = dinv[node];
    float v[8];
    v[0] = fmaf(di, acc[0], bc0.x);
    v[1] = fmaf(di, acc[1], bc0.y);
    v[2] = fmaf(di, acc[2], bc0.z);
    v[3] = fmaf(di, acc[3], bc0.w);
    v[4] = fmaf(di, acc[4], bc1.x);
    v[5] = fmaf(di, acc[5], bc1.y);
    v[6] = fmaf(di, acc[6], bc1.z);
    v[7] = fmaf(di, acc[7], bc1.w);
    if (prev) {
      float4 p0 = ((const float4*)prev)[(size_t)node * 32 + lane * 2];
      float4 p1 = ((const float4*)prev)[(size_t)node * 32 + lane * 2 + 1];
      if (psc) {
        p0.x = fmaxf(fmaf(p0.x, ps0.x, ph0.x), 0.f);
        p0.y = fmaxf(fmaf(p0.y, ps0.y, ph0.y), 0.f);
        p0.z = fmaxf(fmaf(p0.z, ps0.z, ph0.z), 0.f);
        p0.w = fmaxf(fmaf(p0.w, ps0.w, ph0.w), 0.f);
        p1.x = fmaxf(fmaf(p1.x, ps1.x, ph1.x), 0.f);
        p1.y = fmaxf(fmaf(p1.y, ps1.y, ph1.y), 0.f);
        p1.z = fmaxf(fmaf(p1.z, ps1.z, ph1.z), 0.f);
        p1.w = fmaxf(fmaf(p1.w, ps1.w, ph1.w), 0.f);
      }
      v[0] += p0.x; v[1] += p0.y; v[2] += p0.z; v[3] += p0.w;
      v[4] += p1.x; v[5] += p1.y; v[6] += p1.z; v[7] += p1.w;
    }
    ((float4*)out)[(size_t)node * 32 + lane * 2] = make_float4(v[0], v[1], v[2], v[3]);
    ((float4*)out)[(size_t)node * 32 + lane * 2 + 1] = make_float4(v[4], v[5], v[6], v[7]);
#pragma unroll
    for (int j = 0; j < 8; ++j) {
      lsum[j] += v[j];
      lsq[j] = fmaf(v[j], v[j], lsq[j]);
    }
  }

  __shared__ float sred[16][16][8];  // [grp][lane][col] 8 KiB
#pragma unroll
  for (int j = 0; j < 8; ++j) sred[grp][lane][j] = lsum[j];
  __syncthreads();
  if (grp == 0) {
    float s[8];
#pragma unroll
    for (int j = 0; j < 8; ++j) s[j] = sred[0][lane][j];
    for (int g = 1; g < 16; ++g)
#pragma unroll
      for (int j = 0; j < 8; ++j) s[j] += sred[g][lane][j];
#pragma unroll
    for (int j = 0; j < 8; ++j) atomicAdd(&ssum[lane * 8 + j], s[j]);
  }
  __syncthreads();
#pragma unroll
  for (int j = 0; j < 8; ++j) sred[grp][lane][j] = lsq[j];
  __syncthreads();
  if (grp == 0) {
    float s[8];
#pragma unroll
    for (int j = 0; j < 8; ++j) s[j] = sred[0][lane][j];
    for (int g = 1; g < 16; ++g)
#pragma unroll
      for (int j = 0; j < 8; ++j) s[j] += sred[g][lane][j];
#pragma unroll
    for (int j = 0; j < 8; ++j) atomicAdd(&ssq[lane * 8 + j], s[j]);
  }
}

// ---------------- BN finalize + final normalize/relu ----------------

__global__ void k_bn(const float* __restrict__ ssum, const float* __restrict__ ssq,
                     const float* __restrict__ gamma, const float* __restrict__ beta,
                     float* __restrict__ scale, float* __restrict__ shift, float invn) {
  int c = threadIdx.x;
  float mu = ssum[c] * invn;
  float var = ssq[c] * invn - mu * mu;
  float rstd = rsqrtf(var + BN_EPS);
  float sc = rstd * gamma[c];
  scale[c] = sc;
  shift[c] = beta[c] - mu * sc;
}

__global__ __launch_bounds__(256) void k_norm(const float* __restrict__ in,
                                              float* __restrict__ out,
                                              const float* __restrict__ scale,
                                              const float* __restrict__ shift, int n4) {
  int stride = gridDim.x * blockDim.x;
  for (int i = blockIdx.x * blockDim.x + threadIdx.x; i < n4; i += stride) {
    int cg = i & 31;
    float4 sc = ((const float4*)scale)[cg];
    float4 sh = ((const float4*)shift)[cg];
    float4 v = ((const float4*)in)[i];
    v.x = fmaxf(fmaf(v.x, sc.x, sh.x), 0.f);
    v.y = fmaxf(fmaf(v.y, sc.y, sh.y), 0.f);
    v.z = fmaxf(fmaf(v.z, sc.z, sh.z), 0.f);
    v.w = fmaxf(fmaf(v.w, sc.w, sh.w), 0.f);
    ((float4*)out)[i] = v;
  }
}

// ---------------- launch ----------------

extern "C" void kernel_launch(void* const* d_in, const int* in_sizes, int n_in,
                              void* d_out, int out_size, void* d_ws, size_t ws_size,
                              hipStream_t stream) {
  const float* x = (const float*)d_in[0];
  const int* ei = (const int*)d_in[1];
  int n = in_sizes[0] / DIM;   // 100000
  int ne = in_sizes[1] / 2;    // 1600000
  const int* src = ei;
  const int* dst = ei + ne;

  const float *W[3], *B[3], *G[3], *Bt[3];
  if (n_in >= 14) {
    for (int l = 0; l < 3; ++l) {
      W[l] = (const float*)d_in[2 + l];
      B[l] = (const float*)d_in[5 + l];
      G[l] = (const float*)d_in[8 + l];
      Bt[l] = (const float*)d_in[11 + l];
    }
  } else {
    for (int l = 0; l < 3; ++l) {
      W[l] = (const float*)d_in[2] + (size_t)l * DIM * DIM;
      B[l] = (const float*)d_in[3] + (size_t)l * DIM;
      G[l] = (const float*)d_in[4] + (size_t)l * DIM;
      Bt[l] = (const float*)d_in[5] + (size_t)l * DIM;
    }
  }

  float* out = (float*)d_out;

  char* p = (char*)d_ws;
  auto carve = [&](size_t bytes) {
    void* q = (void*)p;
    p += (bytes + 255) & ~(size_t)255;
    return q;
  };
  int* ideg = (int*)carve((size_t)n * 4);
  int* coff = (int*)carve((size_t)(n + 1) * 4);
  int* cur = (int*)carve((size_t)n * 4);
  float* dinv = (float*)carve((size_t)n * 4);
  int* csr_src = (int*)carve((size_t)ne * 4);
  u32* xw = (u32*)carve((size_t)n * DIM * 2);      // bf16 packed
  float* buf1 = (float*)carve((size_t)n * DIM * 4);
  float* stats = (float*)carve(3 * 256 * 4);
  float* scsh = (float*)carve(3 * 256 * 4);

  hipMemsetAsync(ideg, 0, (size_t)n * 4, stream);
  hipMemsetAsync(stats, 0, 3 * 256 * 4, stream);

  k_count<<<1024, 256, 0, stream>>>(dst, ideg, ne);
  k_scan<<<1, 1024, 0, stream>>>(ideg, coff, cur, n);
  k_dinv<<<(n + 255) / 256, 256, 0, stream>>>(ideg, dinv, n);
  k_fill<<<1024, 256, 0, stream>>>(src, dst, cur, csr_src, ne);

  float invn = 1.0f / (float)n;
  int nblk = (n + DIM - 1) / DIM;

  // layer 0: gemm(x) -> xw ; agg -> raw0 in buf1 ; bn -> scsh0
  float* ss0 = stats;         float* sc0 = scsh;
  k_gemm<<<nblk, 256, 0, stream>>>(x, W[0], dinv, nullptr, nullptr, xw, n);
  k_agg<<<2048, 256, 0, stream>>>(xw, coff, csr_src, dinv, B[0], nullptr, nullptr, nullptr,
                                  buf1, ss0, ss0 + 128, n);
  k_bn<<<1, 128, 0, stream>>>(ss0, ss0 + 128, G[0], Bt[0], sc0, sc0 + 128, invn);

  // layer 1: gemm(norm0(buf1)) -> xw ; agg(prev=norm0(buf1)) -> raw1 in d_out ; bn -> scsh1
  float* ss1 = stats + 256;   float* sc1 = scsh + 256;
  k_gemm<<<nblk, 256, 0, stream>>>(buf1, W[1], dinv, sc0, sc0 + 128, xw, n);
  k_agg<<<2048, 256, 0, stream>>>(xw, coff, csr_src, dinv, B[1], buf1, sc0, sc0 + 128,
                                  out, ss1, ss1 + 128, n);
  k_bn<<<1, 128, 0, stream>>>(ss1, ss1 + 128, G[1], Bt[1], sc1, sc1 + 128, invn);

  // layer 2: gemm(norm1(d_out)) -> xw ; agg(prev=norm1(d_out)) -> raw2 in buf1 ; bn -> scsh2
  float* ss2 = stats + 512;   float* sc2 = scsh + 512;
  k_gemm<<<nblk, 256, 0, stream>>>(out, W[2], dinv, sc1, sc1 + 128, xw, n);
  k_agg<<<2048, 256, 0, stream>>>(xw, coff, csr_src, dinv, B[2], out, sc1, sc1 + 128,
                                  buf1, ss2, ss2 + 128, n);
  k_bn<<<1, 128, 0, stream>>>(ss2, ss2 + 128, G[2], Bt[2], sc2, sc2 + 128, invn);

  // final normalize into d_out
  k_norm<<<2048, 256, 0, stream>>>(buf1, out, sc2, sc2 + 128, n * DIM / 4);
}

// Round 5
// 1595.525 us; speedup vs baseline: 1.3259x; 1.3259x over previous
//
#include <hip/hip_runtime.h>

#define DIM 128
#define BN_EPS 1e-5f

// ---------------- CSR build ----------------

__global__ __launch_bounds__(256) void k_count(const int* __restrict__ dst,
                                               int* __restrict__ ideg, int ne) {
  int stride = gridDim.x * blockDim.x;
  for (int e = blockIdx.x * blockDim.x + threadIdx.x; e < ne; e += stride)
    atomicAdd(&ideg[dst[e]], 1);
}

__global__ __launch_bounds__(1024) void k_scan(const int* __restrict__ ideg,
                                               int* __restrict__ off,
                                               int* __restrict__ cur, int n) {
  __shared__ int sums[1024];
  int t = threadIdx.x;
  int chunk = (n + 1023) >> 10;
  int s0 = t * chunk;
  int s1 = s0 + chunk;
  if (s0 > n) s0 = n;
  if (s1 > n) s1 = n;
  int tot = 0;
  for (int i = s0; i < s1; ++i) tot += ideg[i];
  sums[t] = tot;
  __syncthreads();
  for (int d = 1; d < 1024; d <<= 1) {
    int v = (t >= d) ? sums[t - d] : 0;
    __syncthreads();
    sums[t] += v;
    __syncthreads();
  }
  int run = (t == 0) ? 0 : sums[t - 1];
  for (int i = s0; i < s1; ++i) {
    off[i] = run;
    cur[i] = run;
    run += ideg[i];
  }
  if (t == 1023) off[n] = run;
}

__global__ __launch_bounds__(256) void k_dinv(const int* __restrict__ ideg,
                                              float* __restrict__ dinv, int n) {
  int i = blockIdx.x * blockDim.x + threadIdx.x;
  if (i < n) dinv[i] = rsqrtf((float)ideg[i] + 1.0f);  // +1 = self loop
}

__global__ __launch_bounds__(256) void k_fill(const int* __restrict__ src,
                                              const int* __restrict__ dst,
                                              int* __restrict__ cur,
                                              int* __restrict__ csr_src, int ne) {
  int stride = gridDim.x * blockDim.x;
  for (int e = blockIdx.x * blockDim.x + threadIdx.x; e < ne; e += stride) {
    int d = dst[e];
    int s = src[e];
    int p = atomicAdd(&cur[d], 1);
    csr_src[p] = s;
  }
}

// ---------------- GEMM: C[n,128] = dinv[row] * (f(A)[n,128] @ W[128,128]) ----
// f(A) = relu(A*sc+sh) when sc != null (fused BN of previous layer), else A.

__global__ __launch_bounds__(256) void k_gemm(const float* __restrict__ A,
                                              const float* __restrict__ W,
                                              const float* __restrict__ dinv,
                                              const float* __restrict__ sc,
                                              const float* __restrict__ sh,
                                              float* __restrict__ C, int n) {
  __shared__ float sW[DIM][DIM];
  __shared__ float sH[DIM][DIM];
  int tid = threadIdx.x;
  int row0 = blockIdx.x * DIM;

  {
    const float4* Wv = (const float4*)W;
    float4* sWv = (float4*)&sW[0][0];
    for (int i = tid; i < DIM * DIM / 4; i += 256) sWv[i] = Wv[i];
  }
  {
    float4* sHv = (float4*)&sH[0][0];
    for (int i = tid; i < DIM * DIM / 4; i += 256) {
      int r = i >> 5;
      int cg = i & 31;
      int gr = row0 + r;
      float4 v = make_float4(0.f, 0.f, 0.f, 0.f);
      if (gr < n) {
        v = ((const float4*)A)[(size_t)gr * (DIM / 4) + cg];
        if (sc) {
          float4 s4 = ((const float4*)sc)[cg];
          float4 h4 = ((const float4*)sh)[cg];
          v.x = fmaxf(fmaf(v.x, s4.x, h4.x), 0.f);
          v.y = fmaxf(fmaf(v.y, s4.y, h4.y), 0.f);
          v.z = fmaxf(fmaf(v.z, s4.z, h4.z), 0.f);
          v.w = fmaxf(fmaf(v.w, s4.w, h4.w), 0.f);
        }
      }
      sHv[i] = v;
    }
  }
  __syncthreads();

  int tx = tid & 15;
  int ty = tid >> 4;
  int c0 = tx * 8;
  int r0 = ty * 8;
  float acc[8][8];
#pragma unroll
  for (int i = 0; i < 8; ++i)
#pragma unroll
    for (int j = 0; j < 8; ++j) acc[i][j] = 0.f;

  for (int k = 0; k < DIM; ++k) {
    float4 b0 = *(const float4*)&sW[k][c0];
    float4 b1 = *(const float4*)&sW[k][c0 + 4];
    float b[8] = {b0.x, b0.y, b0.z, b0.w, b1.x, b1.y, b1.z, b1.w};
    float a[8];
#pragma unroll
    for (int i = 0; i < 8; ++i) a[i] = sH[r0 + i][k];
#pragma unroll
    for (int i = 0; i < 8; ++i)
#pragma unroll
      for (int j = 0; j < 8; ++j) acc[i][j] = fmaf(a[i], b[j], acc[i][j]);
  }

#pragma unroll
  for (int i = 0; i < 8; ++i) {
    int gr = row0 + r0 + i;
    if (gr < n) {
      float di = dinv[gr];
      float4 v0 = make_float4(di * acc[i][0], di * acc[i][1], di * acc[i][2], di * acc[i][3]);
      float4 v1 = make_float4(di * acc[i][4], di * acc[i][5], di * acc[i][6], di * acc[i][7]);
      float4* cp = (float4*)&C[(size_t)gr * DIM + c0];
      cp[0] = v0;
      cp[1] = v1;
    }
  }
}

// ---------------- Aggregation + bias + residual(BN-fused) + BN partial stats ----
// xw rows pre-scaled by dinv[row]. 32 threads/node, float4/lane, edge unroll 8.
// prev is raw pre-BN f32; if psc given, residual = relu(prev*psc+psh).

__global__ __launch_bounds__(256) void k_agg(const float* __restrict__ xw,
                                             const int* __restrict__ off,
                                             const int* __restrict__ csr_src,
                                             const float* __restrict__ dinv,
                                             const float* __restrict__ bias,
                                             const float* __restrict__ prev,
                                             const float* __restrict__ psc,
                                             const float* __restrict__ psh,
                                             float* __restrict__ out,
                                             float* __restrict__ ssum,
                                             float* __restrict__ ssq, int n) {
  int tid = threadIdx.x;
  int lane = tid & 31;  // column group: cols [lane*4, lane*4+4)
  int grp = tid >> 5;   // 8 node slots per block
  const float4* xw4 = (const float4*)xw;
  float4 bc = ((const float4*)bias)[lane];
  float4 ps, ph;
  if (psc) {
    ps = ((const float4*)psc)[lane];
    ph = ((const float4*)psh)[lane];
  }
  float4 lsum = make_float4(0.f, 0.f, 0.f, 0.f);
  float4 lsq = make_float4(0.f, 0.f, 0.f, 0.f);

  for (int node = blockIdx.x * 8 + grp; node < n; node += gridDim.x * 8) {
    int e0 = off[node];
    int e1 = off[node + 1];
    float4 acc = xw4[(size_t)node * 32 + lane];  // self loop (pre-scaled)
    int e = e0;
    for (; e + 8 <= e1; e += 8) {
      int i0 = csr_src[e];
      int i1 = csr_src[e + 1];
      int i2 = csr_src[e + 2];
      int i3 = csr_src[e + 3];
      int i4 = csr_src[e + 4];
      int i5 = csr_src[e + 5];
      int i6 = csr_src[e + 6];
      int i7 = csr_src[e + 7];
      float4 a0 = xw4[(size_t)i0 * 32 + lane];
      float4 a1 = xw4[(size_t)i1 * 32 + lane];
      float4 a2 = xw4[(size_t)i2 * 32 + lane];
      float4 a3 = xw4[(size_t)i3 * 32 + lane];
      float4 a4 = xw4[(size_t)i4 * 32 + lane];
      float4 a5 = xw4[(size_t)i5 * 32 + lane];
      float4 a6 = xw4[(size_t)i6 * 32 + lane];
      float4 a7 = xw4[(size_t)i7 * 32 + lane];
      acc.x += ((a0.x + a1.x) + (a2.x + a3.x)) + ((a4.x + a5.x) + (a6.x + a7.x));
      acc.y += ((a0.y + a1.y) + (a2.y + a3.y)) + ((a4.y + a5.y) + (a6.y + a7.y));
      acc.z += ((a0.z + a1.z) + (a2.z + a3.z)) + ((a4.z + a5.z) + (a6.z + a7.z));
      acc.w += ((a0.w + a1.w) + (a2.w + a3.w)) + ((a4.w + a5.w) + (a6.w + a7.w));
    }
    for (; e + 4 <= e1; e += 4) {
      int i0 = csr_src[e];
      int i1 = csr_src[e + 1];
      int i2 = csr_src[e + 2];
      int i3 = csr_src[e + 3];
      float4 a0 = xw4[(size_t)i0 * 32 + lane];
      float4 a1 = xw4[(size_t)i1 * 32 + lane];
      float4 a2 = xw4[(size_t)i2 * 32 + lane];
      float4 a3 = xw4[(size_t)i3 * 32 + lane];
      acc.x += (a0.x + a1.x) + (a2.x + a3.x);
      acc.y += (a0.y + a1.y) + (a2.y + a3.y);
      acc.z += (a0.z + a1.z) + (a2.z + a3.z);
      acc.w += (a0.w + a1.w) + (a2.w + a3.w);
    }
    for (; e < e1; ++e) {
      float4 a = xw4[(size_t)csr_src[e] * 32 + lane];
      acc.x += a.x;
      acc.y += a.y;
      acc.z += a.z;
      acc.w += a.w;
    }
    float di = dinv[node];
    float4 v;
    v.x = fmaf(di, acc.x, bc.x);
    v.y = fmaf(di, acc.y, bc.y);
    v.z = fmaf(di, acc.z, bc.z);
    v.w = fmaf(di, acc.w, bc.w);
    if (prev) {
      float4 pv = ((const float4*)prev)[(size_t)node * 32 + lane];
      if (psc) {
        pv.x = fmaxf(fmaf(pv.x, ps.x, ph.x), 0.f);
        pv.y = fmaxf(fmaf(pv.y, ps.y, ph.y), 0.f);
        pv.z = fmaxf(fmaf(pv.z, ps.z, ph.z), 0.f);
        pv.w = fmaxf(fmaf(pv.w, ps.w, ph.w), 0.f);
      }
      v.x += pv.x;
      v.y += pv.y;
      v.z += pv.z;
      v.w += pv.w;
    }
    ((float4*)out)[(size_t)node * 32 + lane] = v;
    lsum.x += v.x;
    lsum.y += v.y;
    lsum.z += v.z;
    lsum.w += v.w;
    lsq.x = fmaf(v.x, v.x, lsq.x);
    lsq.y = fmaf(v.y, v.y, lsq.y);
    lsq.z = fmaf(v.z, v.z, lsq.z);
    lsq.w = fmaf(v.w, v.w, lsq.w);
  }

  __shared__ float4 red[256];
  red[tid] = lsum;
  __syncthreads();
  if (grp == 0) {
    float4 s = red[lane];
#pragma unroll
    for (int g = 1; g < 8; ++g) {
      float4 t = red[g * 32 + lane];
      s.x += t.x;
      s.y += t.y;
      s.z += t.z;
      s.w += t.w;
    }
    atomicAdd(&ssum[lane * 4 + 0], s.x);
    atomicAdd(&ssum[lane * 4 + 1], s.y);
    atomicAdd(&ssum[lane * 4 + 2], s.z);
    atomicAdd(&ssum[lane * 4 + 3], s.w);
  }
  __syncthreads();
  red[tid] = lsq;
  __syncthreads();
  if (grp == 0) {
    float4 s = red[lane];
#pragma unroll
    for (int g = 1; g < 8; ++g) {
      float4 t = red[g * 32 + lane];
      s.x += t.x;
      s.y += t.y;
      s.z += t.z;
      s.w += t.w;
    }
    atomicAdd(&ssq[lane * 4 + 0], s.x);
    atomicAdd(&ssq[lane * 4 + 1], s.y);
    atomicAdd(&ssq[lane * 4 + 2], s.z);
    atomicAdd(&ssq[lane * 4 + 3], s.w);
  }
}

// ---------------- BN finalize + final normalize/relu ----------------

__global__ void k_bn(const float* __restrict__ ssum, const float* __restrict__ ssq,
                     const float* __restrict__ gamma, const float* __restrict__ beta,
                     float* __restrict__ scale, float* __restrict__ shift, float invn) {
  int c = threadIdx.x;
  float mu = ssum[c] * invn;
  float var = ssq[c] * invn - mu * mu;
  float rstd = rsqrtf(var + BN_EPS);
  float sc = rstd * gamma[c];
  scale[c] = sc;
  shift[c] = beta[c] - mu * sc;
}

__global__ __launch_bounds__(256) void k_norm(const float* __restrict__ in,
                                              float* __restrict__ out,
                                              const float* __restrict__ scale,
                                              const float* __restrict__ shift, int n4) {
  int stride = gridDim.x * blockDim.x;
  for (int i = blockIdx.x * blockDim.x + threadIdx.x; i < n4; i += stride) {
    int cg = i & 31;
    float4 sc = ((const float4*)scale)[cg];
    float4 sh = ((const float4*)shift)[cg];
    float4 v = ((const float4*)in)[i];
    v.x = fmaxf(fmaf(v.x, sc.x, sh.x), 0.f);
    v.y = fmaxf(fmaf(v.y, sc.y, sh.y), 0.f);
    v.z = fmaxf(fmaf(v.z, sc.z, sh.z), 0.f);
    v.w = fmaxf(fmaf(v.w, sc.w, sh.w), 0.f);
    ((float4*)out)[i] = v;
  }
}

// ---------------- launch ----------------

extern "C" void kernel_launch(void* const* d_in, const int* in_sizes, int n_in,
                              void* d_out, int out_size, void* d_ws, size_t ws_size,
                              hipStream_t stream) {
  const float* x = (const float*)d_in[0];
  const int* ei = (const int*)d_in[1];
  int n = in_sizes[0] / DIM;   // 100000
  int ne = in_sizes[1] / 2;    // 1600000
  const int* src = ei;
  const int* dst = ei + ne;

  const float *W[3], *B[3], *G[3], *Bt[3];
  if (n_in >= 14) {
    for (int l = 0; l < 3; ++l) {
      W[l] = (const float*)d_in[2 + l];
      B[l] = (const float*)d_in[5 + l];
      G[l] = (const float*)d_in[8 + l];
      Bt[l] = (const float*)d_in[11 + l];
    }
  } else {
    for (int l = 0; l < 3; ++l) {
      W[l] = (const float*)d_in[2] + (size_t)l * DIM * DIM;
      B[l] = (const float*)d_in[3] + (size_t)l * DIM;
      G[l] = (const float*)d_in[4] + (size_t)l * DIM;
      Bt[l] = (const float*)d_in[5] + (size_t)l * DIM;
    }
  }

  float* out = (float*)d_out;

  char* p = (char*)d_ws;
  auto carve = [&](size_t bytes) {
    void* q = (void*)p;
    p += (bytes + 255) & ~(size_t)255;
    return q;
  };
  int* ideg = (int*)carve((size_t)n * 4);
  int* coff = (int*)carve((size_t)(n + 1) * 4);
  int* cur = (int*)carve((size_t)n * 4);
  float* dinv = (float*)carve((size_t)n * 4);
  int* csr_src = (int*)carve((size_t)ne * 4);
  float* xw = (float*)carve((size_t)n * DIM * 4);
  float* buf1 = (float*)carve((size_t)n * DIM * 4);
  float* stats = (float*)carve(3 * 256 * 4);
  float* scsh = (float*)carve(3 * 256 * 4);

  hipMemsetAsync(ideg, 0, (size_t)n * 4, stream);
  hipMemsetAsync(stats, 0, 3 * 256 * 4, stream);

  k_count<<<1024, 256, 0, stream>>>(dst, ideg, ne);
  k_scan<<<1, 1024, 0, stream>>>(ideg, coff, cur, n);
  k_dinv<<<(n + 255) / 256, 256, 0, stream>>>(ideg, dinv, n);
  k_fill<<<1024, 256, 0, stream>>>(src, dst, cur, csr_src, ne);

  float invn = 1.0f / (float)n;
  int nblk = (n + DIM - 1) / DIM;

  // layer 0: gemm(x) -> xw ; agg -> raw0 in buf1 ; bn -> scsh0
  float* ss0 = stats;         float* sc0 = scsh;
  k_gemm<<<nblk, 256, 0, stream>>>(x, W[0], dinv, nullptr, nullptr, xw, n);
  k_agg<<<2048, 256, 0, stream>>>(xw, coff, csr_src, dinv, B[0], nullptr, nullptr, nullptr,
                                  buf1, ss0, ss0 + 128, n);
  k_bn<<<1, 128, 0, stream>>>(ss0, ss0 + 128, G[0], Bt[0], sc0, sc0 + 128, invn);

  // layer 1: gemm(norm0(buf1)) -> xw ; agg(prev=norm0(buf1)) -> raw1 in d_out ; bn -> scsh1
  float* ss1 = stats + 256;   float* sc1 = scsh + 256;
  k_gemm<<<nblk, 256, 0, stream>>>(buf1, W[1], dinv, sc0, sc0 + 128, xw, n);
  k_agg<<<2048, 256, 0, stream>>>(xw, coff, csr_src, dinv, B[1], buf1, sc0, sc0 + 128,
                                  out, ss1, ss1 + 128, n);
  k_bn<<<1, 128, 0, stream>>>(ss1, ss1 + 128, G[1], Bt[1], sc1, sc1 + 128, invn);

  // layer 2: gemm(norm1(d_out)) -> xw ; agg(prev=norm1(d_out)) -> raw2 in buf1 ; bn -> scsh2
  float* ss2 = stats + 512;   float* sc2 = scsh + 512;
  k_gemm<<<nblk, 256, 0, stream>>>(out, W[2], dinv, sc1, sc1 + 128, xw, n);
  k_agg<<<2048, 256, 0, stream>>>(xw, coff, csr_src, dinv, B[2], out, sc1, sc1 + 128,
                                  buf1, ss2, ss2 + 128, n);
  k_bn<<<1, 128, 0, stream>>>(ss2, ss2 + 128, G[2], Bt[2], sc2, sc2 + 128, invn);

  // final normalize into d_out
  k_norm<<<2048, 256, 0, stream>>>(buf1, out, sc2, sc2 + 128, n * DIM / 4);
}

// Round 6
// 1541.971 us; speedup vs baseline: 1.3719x; 1.0347x over previous
//
#include <hip/hip_runtime.h>

#define DIM 128
#define BN_EPS 1e-5f
typedef unsigned int u32;

__device__ __forceinline__ u32 bf16rne(float x) {
  u32 u = __float_as_uint(x);
  return (u + 0x7FFFu + ((u >> 16) & 1u)) >> 16;
}
__device__ __forceinline__ float bflo(u32 u) { return __uint_as_float(u << 16); }
__device__ __forceinline__ float bfhi(u32 u) { return __uint_as_float(u & 0xFFFF0000u); }

// ---------------- CSR build ----------------

__global__ __launch_bounds__(256) void k_count(const int* __restrict__ dst,
                                               int* __restrict__ ideg, int ne) {
  int stride = gridDim.x * blockDim.x;
  for (int e = blockIdx.x * blockDim.x + threadIdx.x; e < ne; e += stride)
    atomicAdd(&ideg[dst[e]], 1);
}

__global__ __launch_bounds__(1024) void k_scan(const int* __restrict__ ideg,
                                               int* __restrict__ off,
                                               int* __restrict__ cur, int n) {
  __shared__ int sums[1024];
  int t = threadIdx.x;
  int chunk = (n + 1023) >> 10;
  int s0 = t * chunk;
  int s1 = s0 + chunk;
  if (s0 > n) s0 = n;
  if (s1 > n) s1 = n;
  int tot = 0;
  for (int i = s0; i < s1; ++i) tot += ideg[i];
  sums[t] = tot;
  __syncthreads();
  for (int d = 1; d < 1024; d <<= 1) {
    int v = (t >= d) ? sums[t - d] : 0;
    __syncthreads();
    sums[t] += v;
    __syncthreads();
  }
  int run = (t == 0) ? 0 : sums[t - 1];
  for (int i = s0; i < s1; ++i) {
    off[i] = run;
    cur[i] = run;
    run += ideg[i];
  }
  if (t == 1023) off[n] = run;
}

__global__ __launch_bounds__(256) void k_dinv(const int* __restrict__ ideg,
                                              float* __restrict__ dinv, int n) {
  int i = blockIdx.x * blockDim.x + threadIdx.x;
  if (i < n) dinv[i] = rsqrtf((float)ideg[i] + 1.0f);  // +1 = self loop
}

__global__ __launch_bounds__(256) void k_fill(const int* __restrict__ src,
                                              const int* __restrict__ dst,
                                              int* __restrict__ cur,
                                              int* __restrict__ csr_src, int ne) {
  int stride = gridDim.x * blockDim.x;
  for (int e = blockIdx.x * blockDim.x + threadIdx.x; e < ne; e += stride) {
    int d = dst[e];
    int s = src[e];
    int p = atomicAdd(&cur[d], 1);
    csr_src[p] = s;
  }
}

// ---------------- GEMM: C_bf16[n,128] = dinv[row] * (f(A)[n,128] @ W[128,128]) ----
// f(A) = relu(A*sc+sh) when sc != null (fused BN of previous layer), else A.
// Output packed bf16: row = 256 B (64 u32).

__global__ __launch_bounds__(256) void k_gemm(const float* __restrict__ A,
                                              const float* __restrict__ W,
                                              const float* __restrict__ dinv,
                                              const float* __restrict__ sc,
                                              const float* __restrict__ sh,
                                              u32* __restrict__ C, int n) {
  __shared__ float sW[DIM][DIM];
  __shared__ float sH[DIM][DIM];
  int tid = threadIdx.x;
  int row0 = blockIdx.x * DIM;

  {
    const float4* Wv = (const float4*)W;
    float4* sWv = (float4*)&sW[0][0];
    for (int i = tid; i < DIM * DIM / 4; i += 256) sWv[i] = Wv[i];
  }
  {
    float4* sHv = (float4*)&sH[0][0];
    for (int i = tid; i < DIM * DIM / 4; i += 256) {
      int r = i >> 5;
      int cg = i & 31;
      int gr = row0 + r;
      float4 v = make_float4(0.f, 0.f, 0.f, 0.f);
      if (gr < n) {
        v = ((const float4*)A)[(size_t)gr * (DIM / 4) + cg];
        if (sc) {
          float4 s4 = ((const float4*)sc)[cg];
          float4 h4 = ((const float4*)sh)[cg];
          v.x = fmaxf(fmaf(v.x, s4.x, h4.x), 0.f);
          v.y = fmaxf(fmaf(v.y, s4.y, h4.y), 0.f);
          v.z = fmaxf(fmaf(v.z, s4.z, h4.z), 0.f);
          v.w = fmaxf(fmaf(v.w, s4.w, h4.w), 0.f);
        }
      }
      sHv[i] = v;
    }
  }
  __syncthreads();

  int tx = tid & 15;
  int ty = tid >> 4;
  int c0 = tx * 8;
  int r0 = ty * 8;
  float acc[8][8];
#pragma unroll
  for (int i = 0; i < 8; ++i)
#pragma unroll
    for (int j = 0; j < 8; ++j) acc[i][j] = 0.f;

  for (int k = 0; k < DIM; ++k) {
    float4 b0 = *(const float4*)&sW[k][c0];
    float4 b1 = *(const float4*)&sW[k][c0 + 4];
    float b[8] = {b0.x, b0.y, b0.z, b0.w, b1.x, b1.y, b1.z, b1.w};
    float a[8];
#pragma unroll
    for (int i = 0; i < 8; ++i) a[i] = sH[r0 + i][k];
#pragma unroll
    for (int i = 0; i < 8; ++i)
#pragma unroll
      for (int j = 0; j < 8; ++j) acc[i][j] = fmaf(a[i], b[j], acc[i][j]);
  }

#pragma unroll
  for (int i = 0; i < 8; ++i) {
    int gr = row0 + r0 + i;
    if (gr < n) {
      float di = dinv[gr];
      uint4 p;
      p.x = bf16rne(di * acc[i][0]) | (bf16rne(di * acc[i][1]) << 16);
      p.y = bf16rne(di * acc[i][2]) | (bf16rne(di * acc[i][3]) << 16);
      p.z = bf16rne(di * acc[i][4]) | (bf16rne(di * acc[i][5]) << 16);
      p.w = bf16rne(di * acc[i][6]) | (bf16rne(di * acc[i][7]) << 16);
      ((uint4*)C)[(size_t)gr * 16 + tx] = p;
    }
  }
}

// ---------------- Aggregation + bias + residual(BN-fused) + BN partial stats ----
// xw rows bf16-packed (256 B), pre-scaled by dinv[row]. 32 lanes/node (uint2 = cols
// [lane*4, lane*4+4)), 2 nodes per wave, edge unroll 8. prev raw pre-BN f32;
// if psc given, residual = relu(prev*psc+psh).

__global__ __launch_bounds__(256) void k_agg(const u32* __restrict__ xw,
                                             const int* __restrict__ off,
                                             const int* __restrict__ csr_src,
                                             const float* __restrict__ dinv,
                                             const float* __restrict__ bias,
                                             const float* __restrict__ prev,
                                             const float* __restrict__ psc,
                                             const float* __restrict__ psh,
                                             float* __restrict__ out,
                                             float* __restrict__ ssum,
                                             float* __restrict__ ssq, int n) {
  int tid = threadIdx.x;
  int lane = tid & 31;  // column group: cols [lane*4, lane*4+4)
  int grp = tid >> 5;   // 8 node slots per block
  const uint2* xw2 = (const uint2*)xw;
  float4 bc = ((const float4*)bias)[lane];
  float4 ps, ph;
  if (psc) {
    ps = ((const float4*)psc)[lane];
    ph = ((const float4*)psh)[lane];
  }
  float4 lsum = make_float4(0.f, 0.f, 0.f, 0.f);
  float4 lsq = make_float4(0.f, 0.f, 0.f, 0.f);

  for (int node = blockIdx.x * 8 + grp; node < n; node += gridDim.x * 8) {
    int e0 = off[node];
    int e1 = off[node + 1];
    float a0, a1, a2, a3;
    {
      uint2 s = xw2[(size_t)node * 32 + lane];  // self loop (pre-scaled)
      a0 = bflo(s.x);
      a1 = bfhi(s.x);
      a2 = bflo(s.y);
      a3 = bfhi(s.y);
    }
    int e = e0;
    for (; e + 8 <= e1; e += 8) {
      int i0 = csr_src[e];
      int i1 = csr_src[e + 1];
      int i2 = csr_src[e + 2];
      int i3 = csr_src[e + 3];
      int i4 = csr_src[e + 4];
      int i5 = csr_src[e + 5];
      int i6 = csr_src[e + 6];
      int i7 = csr_src[e + 7];
      uint2 v0 = xw2[(size_t)i0 * 32 + lane];
      uint2 v1 = xw2[(size_t)i1 * 32 + lane];
      uint2 v2 = xw2[(size_t)i2 * 32 + lane];
      uint2 v3 = xw2[(size_t)i3 * 32 + lane];
      uint2 v4 = xw2[(size_t)i4 * 32 + lane];
      uint2 v5 = xw2[(size_t)i5 * 32 + lane];
      uint2 v6 = xw2[(size_t)i6 * 32 + lane];
      uint2 v7 = xw2[(size_t)i7 * 32 + lane];
      a0 += ((bflo(v0.x) + bflo(v1.x)) + (bflo(v2.x) + bflo(v3.x))) +
            ((bflo(v4.x) + bflo(v5.x)) + (bflo(v6.x) + bflo(v7.x)));
      a1 += ((bfhi(v0.x) + bfhi(v1.x)) + (bfhi(v2.x) + bfhi(v3.x))) +
            ((bfhi(v4.x) + bfhi(v5.x)) + (bfhi(v6.x) + bfhi(v7.x)));
      a2 += ((bflo(v0.y) + bflo(v1.y)) + (bflo(v2.y) + bflo(v3.y))) +
            ((bflo(v4.y) + bflo(v5.y)) + (bflo(v6.y) + bflo(v7.y)));
      a3 += ((bfhi(v0.y) + bfhi(v1.y)) + (bfhi(v2.y) + bfhi(v3.y))) +
            ((bfhi(v4.y) + bfhi(v5.y)) + (bfhi(v6.y) + bfhi(v7.y)));
    }
    for (; e + 4 <= e1; e += 4) {
      int i0 = csr_src[e];
      int i1 = csr_src[e + 1];
      int i2 = csr_src[e + 2];
      int i3 = csr_src[e + 3];
      uint2 v0 = xw2[(size_t)i0 * 32 + lane];
      uint2 v1 = xw2[(size_t)i1 * 32 + lane];
      uint2 v2 = xw2[(size_t)i2 * 32 + lane];
      uint2 v3 = xw2[(size_t)i3 * 32 + lane];
      a0 += (bflo(v0.x) + bflo(v1.x)) + (bflo(v2.x) + bflo(v3.x));
      a1 += (bfhi(v0.x) + bfhi(v1.x)) + (bfhi(v2.x) + bfhi(v3.x));
      a2 += (bflo(v0.y) + bflo(v1.y)) + (bflo(v2.y) + bflo(v3.y));
      a3 += (bfhi(v0.y) + bfhi(v1.y)) + (bfhi(v2.y) + bfhi(v3.y));
    }
    for (; e < e1; ++e) {
      uint2 v = xw2[(size_t)csr_src[e] * 32 + lane];
      a0 += bflo(v.x);
      a1 += bfhi(v.x);
      a2 += bflo(v.y);
      a3 += bfhi(v.y);
    }
    float di = dinv[node];
    float4 v;
    v.x = fmaf(di, a0, bc.x);
    v.y = fmaf(di, a1, bc.y);
    v.z = fmaf(di, a2, bc.z);
    v.w = fmaf(di, a3, bc.w);
    if (prev) {
      float4 pv = ((const float4*)prev)[(size_t)node * 32 + lane];
      if (psc) {
        pv.x = fmaxf(fmaf(pv.x, ps.x, ph.x), 0.f);
        pv.y = fmaxf(fmaf(pv.y, ps.y, ph.y), 0.f);
        pv.z = fmaxf(fmaf(pv.z, ps.z, ph.z), 0.f);
        pv.w = fmaxf(fmaf(pv.w, ps.w, ph.w), 0.f);
      }
      v.x += pv.x;
      v.y += pv.y;
      v.z += pv.z;
      v.w += pv.w;
    }
    ((float4*)out)[(size_t)node * 32 + lane] = v;
    lsum.x += v.x;
    lsum.y += v.y;
    lsum.z += v.z;
    lsum.w += v.w;
    lsq.x = fmaf(v.x, v.x, lsq.x);
    lsq.y = fmaf(v.y, v.y, lsq.y);
    lsq.z = fmaf(v.z, v.z, lsq.z);
    lsq.w = fmaf(v.w, v.w, lsq.w);
  }

  __shared__ float4 red[256];
  red[tid] = lsum;
  __syncthreads();
  if (grp == 0) {
    float4 s = red[lane];
#pragma unroll
    for (int g = 1; g < 8; ++g) {
      float4 t = red[g * 32 + lane];
      s.x += t.x;
      s.y += t.y;
      s.z += t.z;
      s.w += t.w;
    }
    atomicAdd(&ssum[lane * 4 + 0], s.x);
    atomicAdd(&ssum[lane * 4 + 1], s.y);
    atomicAdd(&ssum[lane * 4 + 2], s.z);
    atomicAdd(&ssum[lane * 4 + 3], s.w);
  }
  __syncthreads();
  red[tid] = lsq;
  __syncthreads();
  if (grp == 0) {
    float4 s = red[lane];
#pragma unroll
    for (int g = 1; g < 8; ++g) {
      float4 t = red[g * 32 + lane];
      s.x += t.x;
      s.y += t.y;
      s.z += t.z;
      s.w += t.w;
    }
    atomicAdd(&ssq[lane * 4 + 0], s.x);
    atomicAdd(&ssq[lane * 4 + 1], s.y);
    atomicAdd(&ssq[lane * 4 + 2], s.z);
    atomicAdd(&ssq[lane * 4 + 3], s.w);
  }
}

// ---------------- BN finalize + final normalize/relu ----------------

__global__ void k_bn(const float* __restrict__ ssum, const float* __restrict__ ssq,
                     const float* __restrict__ gamma, const float* __restrict__ beta,
                     float* __restrict__ scale, float* __restrict__ shift, float invn) {
  int c = threadIdx.x;
  float mu = ssum[c] * invn;
  float var = ssq[c] * invn - mu * mu;
  float rstd = rsqrtf(var + BN_EPS);
  float sc = rstd * gamma[c];
  scale[c] = sc;
  shift[c] = beta[c] - mu * sc;
}

__global__ __launch_bounds__(256) void k_norm(const float* __restrict__ in,
                                              float* __restrict__ out,
                                              const float* __restrict__ scale,
                                              const float* __restrict__ shift, int n4) {
  int stride = gridDim.x * blockDim.x;
  for (int i = blockIdx.x * blockDim.x + threadIdx.x; i < n4; i += stride) {
    int cg = i & 31;
    float4 sc = ((const float4*)scale)[cg];
    float4 sh = ((const float4*)shift)[cg];
    float4 v = ((const float4*)in)[i];
    v.x = fmaxf(fmaf(v.x, sc.x, sh.x), 0.f);
    v.y = fmaxf(fmaf(v.y, sc.y, sh.y), 0.f);
    v.z = fmaxf(fmaf(v.z, sc.z, sh.z), 0.f);
    v.w = fmaxf(fmaf(v.w, sc.w, sh.w), 0.f);
    ((float4*)out)[i] = v;
  }
}

// ---------------- launch ----------------

extern "C" void kernel_launch(void* const* d_in, const int* in_sizes, int n_in,
                              void* d_out, int out_size, void* d_ws, size_t ws_size,
                              hipStream_t stream) {
  const float* x = (const float*)d_in[0];
  const int* ei = (const int*)d_in[1];
  int n = in_sizes[0] / DIM;   // 100000
  int ne = in_sizes[1] / 2;    // 1600000
  const int* src = ei;
  const int* dst = ei + ne;

  const float *W[3], *B[3], *G[3], *Bt[3];
  if (n_in >= 14) {
    for (int l = 0; l < 3; ++l) {
      W[l] = (const float*)d_in[2 + l];
      B[l] = (const float*)d_in[5 + l];
      G[l] = (const float*)d_in[8 + l];
      Bt[l] = (const float*)d_in[11 + l];
    }
  } else {
    for (int l = 0; l < 3; ++l) {
      W[l] = (const float*)d_in[2] + (size_t)l * DIM * DIM;
      B[l] = (const float*)d_in[3] + (size_t)l * DIM;
      G[l] = (const float*)d_in[4] + (size_t)l * DIM;
      Bt[l] = (const float*)d_in[5] + (size_t)l * DIM;
    }
  }

  float* out = (float*)d_out;

  char* p = (char*)d_ws;
  auto carve = [&](size_t bytes) {
    void* q = (void*)p;
    p += (bytes + 255) & ~(size_t)255;
    return q;
  };
  int* ideg = (int*)carve((size_t)n * 4);
  int* coff = (int*)carve((size_t)(n + 1) * 4);
  int* cur = (int*)carve((size_t)n * 4);
  float* dinv = (float*)carve((size_t)n * 4);
  int* csr_src = (int*)carve((size_t)ne * 4);
  u32* xw = (u32*)carve((size_t)n * DIM * 2);   // bf16 packed
  float* buf1 = (float*)carve((size_t)n * DIM * 4);
  float* stats = (float*)carve(3 * 256 * 4);
  float* scsh = (float*)carve(3 * 256 * 4);

  hipMemsetAsync(ideg, 0, (size_t)n * 4, stream);
  hipMemsetAsync(stats, 0, 3 * 256 * 4, stream);

  k_count<<<1024, 256, 0, stream>>>(dst, ideg, ne);
  k_scan<<<1, 1024, 0, stream>>>(ideg, coff, cur, n);
  k_dinv<<<(n + 255) / 256, 256, 0, stream>>>(ideg, dinv, n);
  k_fill<<<1024, 256, 0, stream>>>(src, dst, cur, csr_src, ne);

  float invn = 1.0f / (float)n;
  int nblk = (n + DIM - 1) / DIM;

  // layer 0
  float* ss0 = stats;         float* sc0 = scsh;
  k_gemm<<<nblk, 256, 0, stream>>>(x, W[0], dinv, nullptr, nullptr, xw, n);
  k_agg<<<2048, 256, 0, stream>>>(xw, coff, csr_src, dinv, B[0], nullptr, nullptr, nullptr,
                                  buf1, ss0, ss0 + 128, n);
  k_bn<<<1, 128, 0, stream>>>(ss0, ss0 + 128, G[0], Bt[0], sc0, sc0 + 128, invn);

  // layer 1
  float* ss1 = stats + 256;   float* sc1 = scsh + 256;
  k_gemm<<<nblk, 256, 0, stream>>>(buf1, W[1], dinv, sc0, sc0 + 128, xw, n);
  k_agg<<<2048, 256, 0, stream>>>(xw, coff, csr_src, dinv, B[1], buf1, sc0, sc0 + 128,
                                  out, ss1, ss1 + 128, n);
  k_bn<<<1, 128, 0, stream>>>(ss1, ss1 + 128, G[1], Bt[1], sc1, sc1 + 128, invn);

  // layer 2
  float* ss2 = stats + 512;   float* sc2 = scsh + 512;
  k_gemm<<<nblk, 256, 0, stream>>>(out, W[2], dinv, sc1, sc1 + 128, xw, n);
  k_agg<<<2048, 256, 0, stream>>>(xw, coff, csr_src, dinv, B[2], out, sc1, sc1 + 128,
                                  buf1, ss2, ss2 + 128, n);
  k_bn<<<1, 128, 0, stream>>>(ss2, ss2 + 128, G[2], Bt[2], sc2, sc2 + 128, invn);

  // final normalize into d_out
  k_norm<<<2048, 256, 0, stream>>>(buf1, out, sc2, sc2 + 128, n * DIM / 4);
}

// Round 7
// 1302.918 us; speedup vs baseline: 1.6236x; 1.1835x over previous
//
#include <hip/hip_runtime.h>

#define DIM 128
#define BN_EPS 1e-5f
typedef unsigned int u32;
typedef __attribute__((ext_vector_type(8))) short short8;
typedef __attribute__((ext_vector_type(4))) float f32x4;

__device__ __forceinline__ u32 bf16rne(float x) {
  u32 u = __float_as_uint(x);
  return (u + 0x7FFFu + ((u >> 16) & 1u)) >> 16;
}
__device__ __forceinline__ float bflo(u32 u) { return __uint_as_float(u << 16); }
__device__ __forceinline__ float bfhi(u32 u) { return __uint_as_float(u & 0xFFFF0000u); }

// ---------------- CSR build ----------------

__global__ __launch_bounds__(256) void k_count(const int* __restrict__ dst,
                                               int* __restrict__ ideg, int ne) {
  int stride = gridDim.x * blockDim.x;
  for (int e = blockIdx.x * blockDim.x + threadIdx.x; e < ne; e += stride)
    atomicAdd(&ideg[dst[e]], 1);
}

__global__ __launch_bounds__(1024) void k_scan(const int* __restrict__ ideg,
                                               int* __restrict__ off,
                                               int* __restrict__ cur, int n) {
  __shared__ int sums[1024];
  int t = threadIdx.x;
  int chunk = (n + 1023) >> 10;
  int s0 = t * chunk;
  int s1 = s0 + chunk;
  if (s0 > n) s0 = n;
  if (s1 > n) s1 = n;
  int tot = 0;
  for (int i = s0; i < s1; ++i) tot += ideg[i];
  sums[t] = tot;
  __syncthreads();
  for (int d = 1; d < 1024; d <<= 1) {
    int v = (t >= d) ? sums[t - d] : 0;
    __syncthreads();
    sums[t] += v;
    __syncthreads();
  }
  int run = (t == 0) ? 0 : sums[t - 1];
  for (int i = s0; i < s1; ++i) {
    off[i] = run;
    cur[i] = run;
    run += ideg[i];
  }
  if (t == 1023) off[n] = run;
}

__global__ __launch_bounds__(256) void k_dinv(const int* __restrict__ ideg,
                                              float* __restrict__ dinv, int n) {
  int i = blockIdx.x * blockDim.x + threadIdx.x;
  if (i < n) dinv[i] = rsqrtf((float)ideg[i] + 1.0f);  // +1 = self loop
}

__global__ __launch_bounds__(256) void k_fill(const int* __restrict__ src,
                                              const int* __restrict__ dst,
                                              int* __restrict__ cur,
                                              int* __restrict__ csr_src, int ne) {
  int stride = gridDim.x * blockDim.x;
  for (int e = blockIdx.x * blockDim.x + threadIdx.x; e < ne; e += stride) {
    int d = dst[e];
    int s = src[e];
    int p = atomicAdd(&cur[d], 1);
    csr_src[p] = s;
  }
}

// ---------------- W prep: Wt[c][k] bf16-packed, per layer ----------------

__global__ __launch_bounds__(256) void k_wprep(const float* __restrict__ W0,
                                               const float* __restrict__ W1,
                                               const float* __restrict__ W2,
                                               u32* __restrict__ Wt) {
  const float* W = blockIdx.x == 0 ? W0 : (blockIdx.x == 1 ? W1 : W2);
  u32* o = Wt + (size_t)blockIdx.x * DIM * 64;
  int tid = threadIdx.x;
#pragma unroll
  for (int i = 0; i < 32; ++i) {
    int u = tid + i * 256;       // 8192 outputs: Wt[c][kk] = W[2kk][c] | W[2kk+1][c]
    int c = u >> 6;
    int kk = u & 63;
    float lo = W[(size_t)(2 * kk) * DIM + c];
    float hi = W[(size_t)(2 * kk + 1) * DIM + c];
    o[u] = bf16rne(lo) | (bf16rne(hi) << 16);
  }
}

// ---------------- MFMA GEMM: C_bf16[n,128] = dinv[row]*(f(A)[n,128] @ W) ----
// f(A) = relu(A*sc+sh) when sc != null. Wt is bf16-packed W^T (u32[128][64]).
// Block: 128 rows, 4 waves; wave w -> rows [w*32, w*32+32), all 128 cols.

__global__ __launch_bounds__(256) void k_gemm(const float* __restrict__ A,
                                              const u32* __restrict__ Wt,
                                              const float* __restrict__ dinv,
                                              const float* __restrict__ sc,
                                              const float* __restrict__ sh,
                                              u32* __restrict__ C, int n) {
  __shared__ u32 sA[8192];   // 128 rows x 16 slots x 16B, slot-swizzled
  __shared__ u32 sB[8192];   // Wt same layout
  __shared__ float sdv[DIM];
  int tid = threadIdx.x;
  int row0 = blockIdx.x * DIM;

  // stage Wt (already bf16): 2048 uint4 units
  {
    const uint4* w4 = (const uint4*)Wt;
#pragma unroll
    for (int i = 0; i < 8; ++i) {
      int u = tid + i * 256;
      int r = u >> 4, s = u & 15;
      uint4 v = w4[u];
      ((uint4*)sB)[r * 16 + (s ^ (r & 7))] = v;
    }
  }
  // stage A: f32 -> (bn,relu) -> bf16
#pragma unroll
  for (int i = 0; i < 8; ++i) {
    int u = tid + i * 256;
    int r = u >> 4, s = u & 15;
    int gr = row0 + r;
    uint4 pv = make_uint4(0u, 0u, 0u, 0u);
    if (gr < n) {
      float4 v0 = ((const float4*)A)[(size_t)gr * 32 + s * 2];
      float4 v1 = ((const float4*)A)[(size_t)gr * 32 + s * 2 + 1];
      if (sc) {
        float4 s0 = ((const float4*)sc)[s * 2];
        float4 s1 = ((const float4*)sc)[s * 2 + 1];
        float4 h0 = ((const float4*)sh)[s * 2];
        float4 h1 = ((const float4*)sh)[s * 2 + 1];
        v0.x = fmaxf(fmaf(v0.x, s0.x, h0.x), 0.f);
        v0.y = fmaxf(fmaf(v0.y, s0.y, h0.y), 0.f);
        v0.z = fmaxf(fmaf(v0.z, s0.z, h0.z), 0.f);
        v0.w = fmaxf(fmaf(v0.w, s0.w, h0.w), 0.f);
        v1.x = fmaxf(fmaf(v1.x, s1.x, h1.x), 0.f);
        v1.y = fmaxf(fmaf(v1.y, s1.y, h1.y), 0.f);
        v1.z = fmaxf(fmaf(v1.z, s1.z, h1.z), 0.f);
        v1.w = fmaxf(fmaf(v1.w, s1.w, h1.w), 0.f);
      }
      pv.x = bf16rne(v0.x) | (bf16rne(v0.y) << 16);
      pv.y = bf16rne(v0.z) | (bf16rne(v0.w) << 16);
      pv.z = bf16rne(v1.x) | (bf16rne(v1.y) << 16);
      pv.w = bf16rne(v1.z) | (bf16rne(v1.w) << 16);
    }
    ((uint4*)sA)[r * 16 + (s ^ (r & 7))] = pv;
  }
  if (tid < DIM) sdv[tid] = (row0 + tid < n) ? dinv[row0 + tid] : 0.f;
  __syncthreads();

  int lane = tid & 63;
  int w = tid >> 6;
  int lr = lane & 15;
  int g = lane >> 4;
  f32x4 acc[2][8];
#pragma unroll
  for (int m = 0; m < 2; ++m)
#pragma unroll
    for (int nt = 0; nt < 8; ++nt) acc[m][nt] = (f32x4){0.f, 0.f, 0.f, 0.f};

#pragma unroll
  for (int kc = 0; kc < 4; ++kc) {
    short8 a[2], b[8];
#pragma unroll
    for (int m = 0; m < 2; ++m) {
      int r = w * 32 + m * 16 + lr;
      int sp = (kc * 4 + g) ^ (r & 7);
      a[m] = *(const short8*)&sA[(r * 16 + sp) * 4];
    }
#pragma unroll
    for (int nt = 0; nt < 8; ++nt) {
      int r = nt * 16 + lr;
      int sp = (kc * 4 + g) ^ (r & 7);
      b[nt] = *(const short8*)&sB[(r * 16 + sp) * 4];
    }
#pragma unroll
    for (int m = 0; m < 2; ++m)
#pragma unroll
      for (int nt = 0; nt < 8; ++nt)
        acc[m][nt] = __builtin_amdgcn_mfma_f32_16x16x32_bf16(a[m], b[nt], acc[m][nt], 0, 0, 0);
  }
  __syncthreads();

  // epilogue: scale by dinv, pack bf16 into sA (col-block swizzled), copy out
  {
    unsigned short* so = (unsigned short*)sA;
#pragma unroll
    for (int m = 0; m < 2; ++m) {
#pragma unroll
      for (int nt = 0; nt < 8; ++nt) {
#pragma unroll
        for (int r4 = 0; r4 < 4; ++r4) {
          int rl = w * 32 + m * 16 + g * 4 + r4;
          int col = ((nt ^ ((rl >> 2) & 7)) << 4) + lr;  // 16-col-block swizzle
          so[rl * DIM + col] = (unsigned short)bf16rne(acc[m][nt][r4] * sdv[rl]);
        }
      }
    }
  }
  __syncthreads();
#pragma unroll
  for (int i = 0; i < 8; ++i) {
    int u = tid + i * 256;
    int r = u >> 4, s = u & 15;
    if (row0 + r < n) {
      int sswz = (s & 1) | (((s >> 1) ^ ((r >> 2) & 7)) << 1);
      ((uint4*)C)[(size_t)(row0 + r) * 16 + s] = ((uint4*)sA)[r * 16 + sswz];
    }
  }
}

// ---------------- Aggregation + bias + residual(BN-fused) + BN partial stats ----
// (unchanged from R6)

__global__ __launch_bounds__(256) void k_agg(const u32* __restrict__ xw,
                                             const int* __restrict__ off,
                                             const int* __restrict__ csr_src,
                                             const float* __restrict__ dinv,
                                             const float* __restrict__ bias,
                                             const float* __restrict__ prev,
                                             const float* __restrict__ psc,
                                             const float* __restrict__ psh,
                                             float* __restrict__ out,
                                             float* __restrict__ ssum,
                                             float* __restrict__ ssq, int n) {
  int tid = threadIdx.x;
  int lane = tid & 31;
  int grp = tid >> 5;
  const uint2* xw2 = (const uint2*)xw;
  float4 bc = ((const float4*)bias)[lane];
  float4 ps, ph;
  if (psc) {
    ps = ((const float4*)psc)[lane];
    ph = ((const float4*)psh)[lane];
  }
  float4 lsum = make_float4(0.f, 0.f, 0.f, 0.f);
  float4 lsq = make_float4(0.f, 0.f, 0.f, 0.f);

  for (int node = blockIdx.x * 8 + grp; node < n; node += gridDim.x * 8) {
    int e0 = off[node];
    int e1 = off[node + 1];
    float a0, a1, a2, a3;
    {
      uint2 s = xw2[(size_t)node * 32 + lane];
      a0 = bflo(s.x);
      a1 = bfhi(s.x);
      a2 = bflo(s.y);
      a3 = bfhi(s.y);
    }
    int e = e0;
    for (; e + 8 <= e1; e += 8) {
      int i0 = csr_src[e];
      int i1 = csr_src[e + 1];
      int i2 = csr_src[e + 2];
      int i3 = csr_src[e + 3];
      int i4 = csr_src[e + 4];
      int i5 = csr_src[e + 5];
      int i6 = csr_src[e + 6];
      int i7 = csr_src[e + 7];
      uint2 v0 = xw2[(size_t)i0 * 32 + lane];
      uint2 v1 = xw2[(size_t)i1 * 32 + lane];
      uint2 v2 = xw2[(size_t)i2 * 32 + lane];
      uint2 v3 = xw2[(size_t)i3 * 32 + lane];
      uint2 v4 = xw2[(size_t)i4 * 32 + lane];
      uint2 v5 = xw2[(size_t)i5 * 32 + lane];
      uint2 v6 = xw2[(size_t)i6 * 32 + lane];
      uint2 v7 = xw2[(size_t)i7 * 32 + lane];
      a0 += ((bflo(v0.x) + bflo(v1.x)) + (bflo(v2.x) + bflo(v3.x))) +
            ((bflo(v4.x) + bflo(v5.x)) + (bflo(v6.x) + bflo(v7.x)));
      a1 += ((bfhi(v0.x) + bfhi(v1.x)) + (bfhi(v2.x) + bfhi(v3.x))) +
            ((bfhi(v4.x) + bfhi(v5.x)) + (bfhi(v6.x) + bfhi(v7.x)));
      a2 += ((bflo(v0.y) + bflo(v1.y)) + (bflo(v2.y) + bflo(v3.y))) +
            ((bflo(v4.y) + bflo(v5.y)) + (bflo(v6.y) + bflo(v7.y)));
      a3 += ((bfhi(v0.y) + bfhi(v1.y)) + (bfhi(v2.y) + bfhi(v3.y))) +
            ((bfhi(v4.y) + bfhi(v5.y)) + (bfhi(v6.y) + bfhi(v7.y)));
    }
    for (; e + 4 <= e1; e += 4) {
      int i0 = csr_src[e];
      int i1 = csr_src[e + 1];
      int i2 = csr_src[e + 2];
      int i3 = csr_src[e + 3];
      uint2 v0 = xw2[(size_t)i0 * 32 + lane];
      uint2 v1 = xw2[(size_t)i1 * 32 + lane];
      uint2 v2 = xw2[(size_t)i2 * 32 + lane];
      uint2 v3 = xw2[(size_t)i3 * 32 + lane];
      a0 += (bflo(v0.x) + bflo(v1.x)) + (bflo(v2.x) + bflo(v3.x));
      a1 += (bfhi(v0.x) + bfhi(v1.x)) + (bfhi(v2.x) + bfhi(v3.x));
      a2 += (bflo(v0.y) + bflo(v1.y)) + (bflo(v2.y) + bflo(v3.y));
      a3 += (bfhi(v0.y) + bfhi(v1.y)) + (bfhi(v2.y) + bfhi(v3.y));
    }
    for (; e < e1; ++e) {
      uint2 v = xw2[(size_t)csr_src[e] * 32 + lane];
      a0 += bflo(v.x);
      a1 += bfhi(v.x);
      a2 += bflo(v.y);
      a3 += bfhi(v.y);
    }
    float di = dinv[node];
    float4 v;
    v.x = fmaf(di, a0, bc.x);
    v.y = fmaf(di, a1, bc.y);
    v.z = fmaf(di, a2, bc.z);
    v.w = fmaf(di, a3, bc.w);
    if (prev) {
      float4 pv = ((const float4*)prev)[(size_t)node * 32 + lane];
      if (psc) {
        pv.x = fmaxf(fmaf(pv.x, ps.x, ph.x), 0.f);
        pv.y = fmaxf(fmaf(pv.y, ps.y, ph.y), 0.f);
        pv.z = fmaxf(fmaf(pv.z, ps.z, ph.z), 0.f);
        pv.w = fmaxf(fmaf(pv.w, ps.w, ph.w), 0.f);
      }
      v.x += pv.x;
      v.y += pv.y;
      v.z += pv.z;
      v.w += pv.w;
    }
    ((float4*)out)[(size_t)node * 32 + lane] = v;
    lsum.x += v.x;
    lsum.y += v.y;
    lsum.z += v.z;
    lsum.w += v.w;
    lsq.x = fmaf(v.x, v.x, lsq.x);
    lsq.y = fmaf(v.y, v.y, lsq.y);
    lsq.z = fmaf(v.z, v.z, lsq.z);
    lsq.w = fmaf(v.w, v.w, lsq.w);
  }

  __shared__ float4 red[256];
  red[tid] = lsum;
  __syncthreads();
  if (grp == 0) {
    float4 s = red[lane];
#pragma unroll
    for (int g = 1; g < 8; ++g) {
      float4 t = red[g * 32 + lane];
      s.x += t.x;
      s.y += t.y;
      s.z += t.z;
      s.w += t.w;
    }
    atomicAdd(&ssum[lane * 4 + 0], s.x);
    atomicAdd(&ssum[lane * 4 + 1], s.y);
    atomicAdd(&ssum[lane * 4 + 2], s.z);
    atomicAdd(&ssum[lane * 4 + 3], s.w);
  }
  __syncthreads();
  red[tid] = lsq;
  __syncthreads();
  if (grp == 0) {
    float4 s = red[lane];
#pragma unroll
    for (int g = 1; g < 8; ++g) {
      float4 t = red[g * 32 + lane];
      s.x += t.x;
      s.y += t.y;
      s.z += t.z;
      s.w += t.w;
    }
    atomicAdd(&ssq[lane * 4 + 0], s.x);
    atomicAdd(&ssq[lane * 4 + 1], s.y);
    atomicAdd(&ssq[lane * 4 + 2], s.z);
    atomicAdd(&ssq[lane * 4 + 3], s.w);
  }
}

// ---------------- BN finalize + final normalize/relu ----------------

__global__ void k_bn(const float* __restrict__ ssum, const float* __restrict__ ssq,
                     const float* __restrict__ gamma, const float* __restrict__ beta,
                     float* __restrict__ scale, float* __restrict__ shift, float invn) {
  int c = threadIdx.x;
  float mu = ssum[c] * invn;
  float var = ssq[c] * invn - mu * mu;
  float rstd = rsqrtf(var + BN_EPS);
  float s = rstd * gamma[c];
  scale[c] = s;
  shift[c] = beta[c] - mu * s;
}

__global__ __launch_bounds__(256) void k_norm(const float* __restrict__ in,
                                              float* __restrict__ out,
                                              const float* __restrict__ scale,
                                              const float* __restrict__ shift, int n4) {
  int stride = gridDim.x * blockDim.x;
  for (int i = blockIdx.x * blockDim.x + threadIdx.x; i < n4; i += stride) {
    int cg = i & 31;
    float4 sc = ((const float4*)scale)[cg];
    float4 sh = ((const float4*)shift)[cg];
    float4 v = ((const float4*)in)[i];
    v.x = fmaxf(fmaf(v.x, sc.x, sh.x), 0.f);
    v.y = fmaxf(fmaf(v.y, sc.y, sh.y), 0.f);
    v.z = fmaxf(fmaf(v.z, sc.z, sh.z), 0.f);
    v.w = fmaxf(fmaf(v.w, sc.w, sh.w), 0.f);
    ((float4*)out)[i] = v;
  }
}

// ---------------- launch ----------------

extern "C" void kernel_launch(void* const* d_in, const int* in_sizes, int n_in,
                              void* d_out, int out_size, void* d_ws, size_t ws_size,
                              hipStream_t stream) {
  const float* x = (const float*)d_in[0];
  const int* ei = (const int*)d_in[1];
  int n = in_sizes[0] / DIM;   // 100000
  int ne = in_sizes[1] / 2;    // 1600000
  const int* src = ei;
  const int* dst = ei + ne;

  const float *W[3], *B[3], *G[3], *Bt[3];
  if (n_in >= 14) {
    for (int l = 0; l < 3; ++l) {
      W[l] = (const float*)d_in[2 + l];
      B[l] = (const float*)d_in[5 + l];
      G[l] = (const float*)d_in[8 + l];
      Bt[l] = (const float*)d_in[11 + l];
    }
  } else {
    for (int l = 0; l < 3; ++l) {
      W[l] = (const float*)d_in[2] + (size_t)l * DIM * DIM;
      B[l] = (const float*)d_in[3] + (size_t)l * DIM;
      G[l] = (const float*)d_in[4] + (size_t)l * DIM;
      Bt[l] = (const float*)d_in[5] + (size_t)l * DIM;
    }
  }

  float* out = (float*)d_out;

  char* p = (char*)d_ws;
  auto carve = [&](size_t bytes) {
    void* q = (void*)p;
    p += (bytes + 255) & ~(size_t)255;
    return q;
  };
  int* ideg = (int*)carve((size_t)n * 4);
  int* coff = (int*)carve((size_t)(n + 1) * 4);
  int* cur = (int*)carve((size_t)n * 4);
  float* dinv = (float*)carve((size_t)n * 4);
  int* csr_src = (int*)carve((size_t)ne * 4);
  u32* xw = (u32*)carve((size_t)n * DIM * 2);   // bf16 packed
  float* buf1 = (float*)carve((size_t)n * DIM * 4);
  u32* wt = (u32*)carve(3 * DIM * 64 * 4);      // bf16-packed W^T x3
  float* stats = (float*)carve(3 * 256 * 4);
  float* scsh = (float*)carve(3 * 256 * 4);

  hipMemsetAsync(ideg, 0, (size_t)n * 4, stream);
  hipMemsetAsync(stats, 0, 3 * 256 * 4, stream);

  k_wprep<<<3, 256, 0, stream>>>(W[0], W[1], W[2], wt);
  k_count<<<1024, 256, 0, stream>>>(dst, ideg, ne);
  k_scan<<<1, 1024, 0, stream>>>(ideg, coff, cur, n);
  k_dinv<<<(n + 255) / 256, 256, 0, stream>>>(ideg, dinv, n);
  k_fill<<<1024, 256, 0, stream>>>(src, dst, cur, csr_src, ne);

  float invn = 1.0f / (float)n;
  int nblk = (n + DIM - 1) / DIM;

  // layer 0
  float* ss0 = stats;         float* sc0 = scsh;
  k_gemm<<<nblk, 256, 0, stream>>>(x, wt, dinv, nullptr, nullptr, xw, n);
  k_agg<<<2048, 256, 0, stream>>>(xw, coff, csr_src, dinv, B[0], nullptr, nullptr, nullptr,
                                  buf1, ss0, ss0 + 128, n);
  k_bn<<<1, 128, 0, stream>>>(ss0, ss0 + 128, G[0], Bt[0], sc0, sc0 + 128, invn);

  // layer 1
  float* ss1 = stats + 256;   float* sc1 = scsh + 256;
  k_gemm<<<nblk, 256, 0, stream>>>(buf1, wt + (size_t)DIM * 64, dinv, sc0, sc0 + 128, xw, n);
  k_agg<<<2048, 256, 0, stream>>>(xw, coff, csr_src, dinv, B[1], buf1, sc0, sc0 + 128,
                                  out, ss1, ss1 + 128, n);
  k_bn<<<1, 128, 0, stream>>>(ss1, ss1 + 128, G[1], Bt[1], sc1, sc1 + 128, invn);

  // layer 2
  float* ss2 = stats + 512;   float* sc2 = scsh + 512;
  k_gemm<<<nblk, 256, 0, stream>>>(out, wt + (size_t)2 * DIM * 64, dinv, sc1, sc1 + 128, xw, n);
  k_agg<<<2048, 256, 0, stream>>>(xw, coff, csr_src, dinv, B[2], out, sc1, sc1 + 128,
                                  buf1, ss2, ss2 + 128, n);
  k_bn<<<1, 128, 0, stream>>>(ss2, ss2 + 128, G[2], Bt[2], sc2, sc2 + 128, invn);

  // final normalize into d_out
  k_norm<<<2048, 256, 0, stream>>>(buf1, out, sc2, sc2 + 128, n * DIM / 4);
}